// Round 10
// baseline (5550.839 us; speedup 1.0000x reference)
//
#include <hip/hip_runtime.h>
#include <hip/hip_fp16.h>

#define NN 50000
#define NE 300000
#define ETILES (NE / 16)
#define NTILES (NN / 16)
#define WLDS_STRIDE 136
#define NPAD 50048              // padded node count for column-major h

typedef _Float16 f16;
typedef _Float16 f16x4 __attribute__((ext_vector_type(4)));
typedef float f32x4 __attribute__((ext_vector_type(4)));

__device__ __forceinline__ f16x4 cvt4(float4 v) {
    f16x4 r; r.x = (f16)v.x; r.y = (f16)v.y; r.z = (f16)v.z; r.w = (f16)v.w;
    return r;
}

// ---------------- init (full path): xh = x (f16) AND hcm[k][node] = 2*x[node][k] ----------------
__global__ void init_cm_kernel(const float* __restrict__ x0, const float* __restrict__ x1,
                               const float* __restrict__ x2,
                               f16* __restrict__ xhbase, float* __restrict__ hcm) {
    __shared__ float xt[64][65];   // 65 stride -> conflict-free column reads
    const int lvl  = blockIdx.y;
    const int base = blockIdx.x * 64;
    const float* xs = (lvl == 0) ? x0 : (lvl == 1) ? x1 : x2;
    const int t = threadIdx.x;

    for (int i = t; i < 1024; i += 256) {
        const int nl = i >> 4, c4 = i & 15;
        const int node = base + nl;
        float4 v = make_float4(0.f, 0.f, 0.f, 0.f);
        if (node < NN) v = ((const float4*)xs)[(size_t)node * 16 + c4];
        xt[nl][c4 * 4 + 0] = 2.f * v.x; xt[nl][c4 * 4 + 1] = 2.f * v.y;
        xt[nl][c4 * 4 + 2] = 2.f * v.z; xt[nl][c4 * 4 + 3] = 2.f * v.w;
        if (node < NN) {
            f16x4 o; o.x = (f16)v.x; o.y = (f16)v.y; o.z = (f16)v.z; o.w = (f16)v.w;
            ((f16x4*)(xhbase + (size_t)lvl * NN * 64))[(size_t)node * 16 + c4] = o;
        }
    }
    __syncthreads();

    float* h = hcm + (size_t)lvl * 64 * NPAD;
    for (int i = t; i < 4096; i += 256) {
        const int kk = i >> 6, nn = i & 63;
        h[(size_t)kk * NPAD + base + nn] = xt[nn][kk];
    }
}

// ---------------- init (fallback): h = 2*x AND xh = x (both f16) ----------------
__global__ void init2_kernel(const float* __restrict__ x0, const float* __restrict__ x1,
                             const float* __restrict__ x2,
                             f16* __restrict__ hbase, f16* __restrict__ xhbase) {
    const size_t i = (size_t)blockIdx.x * 256 + threadIdx.x;
    const int lvl = (int)(i / (NN * 16));
    const size_t li = i - (size_t)lvl * (NN * 16);
    const float* xs = (lvl == 0) ? x0 : (lvl == 1) ? x1 : x2;
    float4 v = ((const float4*)xs)[li];
    f16x4 xo, ho;
    xo.x = (f16)v.x;        xo.y = (f16)v.y;        xo.z = (f16)v.z;        xo.w = (f16)v.w;
    ho.x = (f16)(2.f*v.x);  ho.y = (f16)(2.f*v.y);  ho.z = (f16)(2.f*v.z);  ho.w = (f16)(2.f*v.w);
    ((f16x4*)(xhbase + (size_t)lvl * NN * 64))[li] = xo;
    ((f16x4*)(hbase  + (size_t)lvl * NN * 64))[li] = ho;
}

// ---------------- W transpose: Wt[c][k] = (f16)W[k][c], W is [128][64] ----------------
__global__ void wtrans_kernel(const float* __restrict__ WU, const float* __restrict__ WD,
                              f16* __restrict__ WtU, f16* __restrict__ WtD) {
    const int i = blockIdx.x * 256 + threadIdx.x;   // 8192
    const int k = i >> 6, c = i & 63;
    WtU[c * 128 + k] = (f16)WU[i];
    WtD[c * 128 + k] = (f16)WD[i];
}

__device__ __forceinline__ int ld_comb(const int* __restrict__ idx, int tile, int l5) {
    const int e0 = tile << 4;
    return idx[(l5 < 16) ? (NE + e0 + l5) : (e0 + l5 - 16)];
}

// ================= edge MLP + COLUMN-MAJOR f32 atomic scatter =================
__global__ __launch_bounds__(256) void edge_cm_kernel(
    const f16* __restrict__ xh,
    const int* __restrict__ ui, const int* __restrict__ di,
    const float* __restrict__ ua, const float* __restrict__ da,
    const f16* __restrict__ WtU, const f16* __restrict__ WtD,
    const float* __restrict__ bU, const float* __restrict__ bD,
    float* __restrict__ h) {            // h: [64 feats][NPAD nodes], this level

    __shared__ __align__(16) f16 Wlds[64 * WLDS_STRIDE];

    const int dir = blockIdx.y;
    const int* __restrict__ idx    = dir ? di : ui;
    const float* __restrict__ attr = dir ? da : ua;
    const f16* __restrict__ Wt     = dir ? WtD : WtU;
    const float* __restrict__ b    = dir ? bD : bU;

    const int tt   = threadIdx.x;
    const int lane = tt & 63;
    const int wid  = tt >> 6;
    const int lr   = lane & 15;
    const int lg   = (lane >> 4) & 3;
    const int l5   = lane & 31;

    for (int i = tt; i < 2048; i += 256) {
        const int row = i >> 5, seg = i & 31;
        *(f16x4*)&Wlds[row * WLDS_STRIDE + seg * 4] = *(const f16x4*)&Wt[row * 128 + seg * 4];
    }
    float bf[4];
#pragma unroll
    for (int n = 0; n < 4; ++n) bf[n] = b[n * 16 + lr];
    __syncthreads();

    const float4* a4 = (const float4*)attr;
    const int S = gridDim.x * 4;
    int t = blockIdx.x * 4 + wid;
    if (t >= ETILES) return;

    for (; t < ETILES; t += S) {
        const int e0 = t << 4;
        const int cA = ld_comb(idx, t, l5);
        const int src = __shfl(cA, lr);
        int tg[4];
#pragma unroll
        for (int j = 0; j < 4; ++j) tg[j] = __shfl(cA, 16 + 4 * lg + j);

        f16x4 afr[8];
#pragma unroll
        for (int k0 = 0; k0 < 4; ++k0)
            afr[k0] = *(const f16x4*)&xh[(size_t)src * 64 + k0 * 16 + 4 * lg];
#pragma unroll
        for (int k0 = 0; k0 < 4; ++k0)
            afr[4 + k0] = cvt4(a4[(size_t)(e0 + lr) * 16 + 4 * k0 + lg]);

        f32x4 acc[4];
#pragma unroll
        for (int n = 0; n < 4; ++n) acc[n] = (f32x4){0.f, 0.f, 0.f, 0.f};
#pragma unroll
        for (int k0 = 0; k0 < 8; ++k0)
#pragma unroll
            for (int n = 0; n < 4; ++n) {
                const f16x4 wfv = *(const f16x4*)&Wlds[(n * 16 + lr) * WLDS_STRIDE + k0 * 16 + 4 * lg];
                acc[n] = __builtin_amdgcn_mfma_f32_16x16x16f16(afr[k0], wfv, acc[n], 0, 0, 0);
            }

        // bias + relu + column-major scatter: each add -> its own cache line
        // D[row=4*lg+j][col=n*16+lr]; addr = feat*NPAD + target
#pragma unroll
        for (int j = 0; j < 4; ++j) {
            const int tgt = tg[j];
#pragma unroll
            for (int n = 0; n < 4; ++n) {
                const float v = fmaxf(acc[n][j] + bf[n], 0.f);
                unsafeAtomicAdd(&h[(size_t)(n * 16 + lr) * NPAD + tgt], v);
            }
        }
    }
}

// ---------------- node MLP reading column-major f32 h ----------------
__global__ __launch_bounds__(256) void node_cm_kernel(
    const float* __restrict__ hcm, float* __restrict__ outb,
    const float* __restrict__ W1, const float* __restrict__ b1,
    const float* __restrict__ W2, const float* __restrict__ b2) {

    __shared__ f16 Y[4][16 * 72];

    const int t    = threadIdx.x;
    const int lane = t & 63;
    const int wid  = t >> 6;
    const int lr   = lane & 15;
    const int lg   = (lane >> 4) & 3;

    f16x4 w1f[4][4], w2f[4][4];
#pragma unroll
    for (int k0 = 0; k0 < 4; ++k0) {
        const int kb = k0 * 16 + 4 * lg;
#pragma unroll
        for (int n = 0; n < 4; ++n) {
            const int c = n * 16 + lr;
            f16x4 wv;
            wv.x = (f16)W1[(kb + 0) * 64 + c];
            wv.y = (f16)W1[(kb + 1) * 64 + c];
            wv.z = (f16)W1[(kb + 2) * 64 + c];
            wv.w = (f16)W1[(kb + 3) * 64 + c];
            w1f[k0][n] = wv;
            wv.x = (f16)W2[(kb + 0) * 64 + c];
            wv.y = (f16)W2[(kb + 1) * 64 + c];
            wv.z = (f16)W2[(kb + 2) * 64 + c];
            wv.w = (f16)W2[(kb + 3) * 64 + c];
            w2f[k0][n] = wv;
        }
    }
    float b1f[4], b2f[4];
#pragma unroll
    for (int n = 0; n < 4; ++n) {
        b1f[n] = b1[n * 16 + lr];
        b2f[n] = b2[n * 16 + lr];
    }

    const int gw     = blockIdx.x * 4 + wid;
    const int stride = gridDim.x * 4;
    for (int tile = gw; tile < 3 * NTILES; tile += stride) {
        const int lvl = tile / NTILES;
        const int n0  = (tile - lvl * NTILES) << 4;
        float* out = outb + (size_t)lvl * NN * 64;
        const float* h = hcm + (size_t)lvl * 64 * NPAD;

        // a[k0].j = (f16)h[k0*16+4*lg+j][n0+lr]  (transposed read)
        f16x4 a[4];
#pragma unroll
        for (int k0 = 0; k0 < 4; ++k0) {
            f16x4 tv;
#pragma unroll
            for (int j = 0; j < 4; ++j)
                tv[j] = (f16)h[(size_t)(k0 * 16 + 4 * lg + j) * NPAD + n0 + lr];
            a[k0] = tv;
        }

        f32x4 acc[4];
#pragma unroll
        for (int n = 0; n < 4; ++n) acc[n] = (f32x4){0.f, 0.f, 0.f, 0.f};
#pragma unroll
        for (int k0 = 0; k0 < 4; ++k0)
#pragma unroll
            for (int n = 0; n < 4; ++n)
                acc[n] = __builtin_amdgcn_mfma_f32_16x16x16f16(a[k0], w1f[k0][n], acc[n], 0, 0, 0);

#pragma unroll
        for (int n = 0; n < 4; ++n)
#pragma unroll
            for (int j = 0; j < 4; ++j) {
                float v = acc[n][j] + b1f[n];
                v = v > 0.f ? v : 0.f;
                Y[wid][(4 * lg + j) * 72 + n * 16 + lr] = (f16)v;
            }

        f16x4 a2[4];
#pragma unroll
        for (int k0 = 0; k0 < 4; ++k0)
            a2[k0] = *(const f16x4*)&Y[wid][lr * 72 + k0 * 16 + 4 * lg];

        f32x4 acc2[4];
#pragma unroll
        for (int n = 0; n < 4; ++n) acc2[n] = (f32x4){0.f, 0.f, 0.f, 0.f};
#pragma unroll
        for (int k0 = 0; k0 < 4; ++k0)
#pragma unroll
            for (int n = 0; n < 4; ++n)
                acc2[n] = __builtin_amdgcn_mfma_f32_16x16x16f16(a2[k0], w2f[k0][n], acc2[n], 0, 0, 0);

#pragma unroll
        for (int n = 0; n < 4; ++n)
#pragma unroll
            for (int j = 0; j < 4; ++j) {
                float v = acc2[n][j] + b2f[n];
                v = v > 0.f ? v : 0.f;
                out[(size_t)(n0 + 4 * lg + j) * 64 + n * 16 + lr] = v;
            }
    }
}

// ================= Fallback (round-5 proven): edge MLP + f16 atomic scatter =================
__global__ __launch_bounds__(256) void edge4_kernel(
    const f16* __restrict__ xh,
    const int* __restrict__ ui, const int* __restrict__ di,
    const float* __restrict__ ua, const float* __restrict__ da,
    const f16* __restrict__ WtU, const f16* __restrict__ WtD,
    const float* __restrict__ bU, const float* __restrict__ bD,
    __half* __restrict__ h) {

    __shared__ __align__(16) f16 Wlds[64 * WLDS_STRIDE];

    const int dir = blockIdx.y;
    const int* __restrict__ idx    = dir ? di : ui;
    const float* __restrict__ attr = dir ? da : ua;
    const f16* __restrict__ Wt     = dir ? WtD : WtU;
    const float* __restrict__ b    = dir ? bD : bU;

    const int tt   = threadIdx.x;
    const int lane = tt & 63;
    const int wid  = tt >> 6;
    const int lr   = lane & 15;
    const int lg   = (lane >> 4) & 3;
    const int l5   = lane & 31;

    for (int i = tt; i < 2048; i += 256) {
        const int row = i >> 5, seg = i & 31;
        *(f16x4*)&Wlds[row * WLDS_STRIDE + seg * 4] = *(const f16x4*)&Wt[row * 128 + seg * 4];
    }
    float bf[4];
#pragma unroll
    for (int n = 0; n < 4; ++n) bf[n] = b[n * 16 + lr];
    __syncthreads();

    const float4* a4 = (const float4*)attr;
    const int S = gridDim.x * 4;
    int t = blockIdx.x * 4 + wid;
    if (t >= ETILES) return;

    for (; t < ETILES; t += S) {
        const int e0 = t << 4;
        const int cA = ld_comb(idx, t, l5);
        const int src = __shfl(cA, lr);
        int tg[4];
#pragma unroll
        for (int j = 0; j < 4; ++j) tg[j] = __shfl(cA, 16 + 4 * lg + j);

        f16x4 afr[8];
#pragma unroll
        for (int k0 = 0; k0 < 4; ++k0)
            afr[k0] = *(const f16x4*)&xh[(size_t)src * 64 + k0 * 16 + 4 * lg];
#pragma unroll
        for (int k0 = 0; k0 < 4; ++k0)
            afr[4 + k0] = cvt4(a4[(size_t)(e0 + lr) * 16 + 4 * k0 + lg]);

        f32x4 acc[4];
#pragma unroll
        for (int n = 0; n < 4; ++n) acc[n] = (f32x4){0, 0, 0, 0};
#pragma unroll
        for (int k0 = 0; k0 < 8; ++k0)
#pragma unroll
            for (int n = 0; n < 4; ++n) {
                const f16x4 wfv = *(const f16x4*)&Wlds[(n * 16 + lr) * WLDS_STRIDE + k0 * 16 + 4 * lg];
                acc[n] = __builtin_amdgcn_mfma_f32_16x16x16f16(afr[k0], wfv, acc[n], 0, 0, 0);
            }

#pragma unroll
        for (int j = 0; j < 4; ++j) {
            float v[4], vn[4];
#pragma unroll
            for (int n = 0; n < 4; ++n) v[n] = fmaxf(acc[n][j] + bf[n], 0.f);
#pragma unroll
            for (int n = 0; n < 4; ++n) vn[n] = __shfl_xor(v[n], 1);
            __half* hp = h + (size_t)tg[j] * 64;
            if ((lane & 1) == 0) {
                unsafeAtomicAdd((__half2*)(hp + 0 * 16 + lr), __floats2half2_rn(v[0], vn[0]));
                unsafeAtomicAdd((__half2*)(hp + 1 * 16 + lr), __floats2half2_rn(v[1], vn[1]));
            } else {
                unsafeAtomicAdd((__half2*)(hp + 2 * 16 + lr - 1), __floats2half2_rn(vn[2], v[2]));
                unsafeAtomicAdd((__half2*)(hp + 3 * 16 + lr - 1), __floats2half2_rn(vn[3], v[3]));
            }
        }
    }
}

__global__ __launch_bounds__(256) void node_kernel(
    const f16* __restrict__ hbase, float* __restrict__ outb,
    const float* __restrict__ W1, const float* __restrict__ b1,
    const float* __restrict__ W2, const float* __restrict__ b2) {

    __shared__ f16 Y[4][16 * 72];

    const int t    = threadIdx.x;
    const int lane = t & 63;
    const int wid  = t >> 6;
    const int lr   = lane & 15;
    const int lg   = (lane >> 4) & 3;

    f16x4 w1f[4][4], w2f[4][4];
#pragma unroll
    for (int k0 = 0; k0 < 4; ++k0) {
        const int kb = k0 * 16 + 4 * lg;
#pragma unroll
        for (int n = 0; n < 4; ++n) {
            const int c = n * 16 + lr;
            f16x4 wv;
            wv.x = (f16)W1[(kb + 0) * 64 + c];
            wv.y = (f16)W1[(kb + 1) * 64 + c];
            wv.z = (f16)W1[(kb + 2) * 64 + c];
            wv.w = (f16)W1[(kb + 3) * 64 + c];
            w1f[k0][n] = wv;
            wv.x = (f16)W2[(kb + 0) * 64 + c];
            wv.y = (f16)W2[(kb + 1) * 64 + c];
            wv.z = (f16)W2[(kb + 2) * 64 + c];
            wv.w = (f16)W2[(kb + 3) * 64 + c];
            w2f[k0][n] = wv;
        }
    }
    float b1f[4], b2f[4];
#pragma unroll
    for (int n = 0; n < 4; ++n) {
        b1f[n] = b1[n * 16 + lr];
        b2f[n] = b2[n * 16 + lr];
    }

    const int gw     = blockIdx.x * 4 + wid;
    const int stride = gridDim.x * 4;
    for (int tile = gw; tile < 3 * NTILES; tile += stride) {
        const int lvl = tile / NTILES;
        const int n0  = (tile - lvl * NTILES) << 4;
        float* out = outb + (size_t)lvl * NN * 64;
        const f16* h16 = hbase + (size_t)lvl * NN * 64;

        f16x4 a[4];
#pragma unroll
        for (int k0 = 0; k0 < 4; ++k0)
            a[k0] = *(const f16x4*)&h16[(size_t)(n0 + lr) * 64 + k0 * 16 + 4 * lg];

        f32x4 acc[4];
#pragma unroll
        for (int n = 0; n < 4; ++n) acc[n] = (f32x4){0, 0, 0, 0};
#pragma unroll
        for (int k0 = 0; k0 < 4; ++k0)
#pragma unroll
            for (int n = 0; n < 4; ++n)
                acc[n] = __builtin_amdgcn_mfma_f32_16x16x16f16(a[k0], w1f[k0][n], acc[n], 0, 0, 0);

#pragma unroll
        for (int n = 0; n < 4; ++n)
#pragma unroll
            for (int j = 0; j < 4; ++j) {
                float v = acc[n][j] + b1f[n];
                v = v > 0.f ? v : 0.f;
                Y[wid][(4 * lg + j) * 72 + n * 16 + lr] = (f16)v;
            }

        f16x4 a2[4];
#pragma unroll
        for (int k0 = 0; k0 < 4; ++k0)
            a2[k0] = *(const f16x4*)&Y[wid][lr * 72 + k0 * 16 + 4 * lg];

        f32x4 acc2[4];
#pragma unroll
        for (int n = 0; n < 4; ++n) acc2[n] = (f32x4){0, 0, 0, 0};
#pragma unroll
        for (int k0 = 0; k0 < 4; ++k0)
#pragma unroll
            for (int n = 0; n < 4; ++n)
                acc2[n] = __builtin_amdgcn_mfma_f32_16x16x16f16(a2[k0], w2f[k0][n], acc2[n], 0, 0, 0);

#pragma unroll
        for (int n = 0; n < 4; ++n)
#pragma unroll
            for (int j = 0; j < 4; ++j) {
                float v = acc2[n][j] + b2f[n];
                v = v > 0.f ? v : 0.f;
                out[(size_t)(n0 + 4 * lg + j) * 64 + n * 16 + lr] = v;
            }
    }
}

extern "C" void kernel_launch(void* const* d_in, const int* in_sizes, int n_in,
                              void* d_out, int out_size, void* d_ws, size_t ws_size,
                              hipStream_t stream) {
    (void)in_sizes; (void)n_in; (void)out_size;

    const float* W_up   = (const float*)d_in[15];
    const float* b_up   = (const float*)d_in[16];
    const float* W_down = (const float*)d_in[17];
    const float* b_down = (const float*)d_in[18];
    const float* W1     = (const float*)d_in[19];
    const float* b1     = (const float*)d_in[20];
    const float* W2     = (const float*)d_in[21];
    const float* b2     = (const float*)d_in[22];

    const float* x0 = (const float*)d_in[0];
    const float* x1 = (const float*)d_in[5];
    const float* x2 = (const float*)d_in[10];

    size_t off = 0;
    auto alloc = [&](size_t bytes) { size_t o = off; off = (off + bytes + 255) & ~(size_t)255; return o; };
    const size_t o_xh  = alloc((size_t)3 * NN * 64 * 2);         // f16 x copies
    const size_t o_agg = alloc((size_t)3 * NN * 64 * 2);         // f16 h (fallback only)
    const size_t o_wt  = alloc((size_t)2 * 128 * 64 * 2);        // Wt f16
    const size_t fallback_need = off;
    const size_t o_hcm = alloc((size_t)3 * 64 * NPAD * 4);       // column-major f32 h
    const size_t full_need = off;

    char* ws = (char*)d_ws;
    f16* xh  = (f16*)(ws + o_xh);
    f16* agg = (f16*)(ws + o_agg);
    f16* WtU = (f16*)(ws + o_wt);
    f16* WtD = WtU + 128 * 64;

    if (ws_size >= full_need) {
        float* hcm = (float*)(ws + o_hcm);

        wtrans_kernel<<<32, 256, 0, stream>>>(W_up, W_down, WtU, WtD);
        init_cm_kernel<<<dim3(782, 3), 256, 0, stream>>>(x0, x1, x2, xh, hcm);

        for (int d = 0; d < 3; ++d) {
            const int*   ui = (const int*)  d_in[5 * d + 1];
            const int*   di = (const int*)  d_in[5 * d + 2];
            const float* ua = (const float*)d_in[5 * d + 3];
            const float* da = (const float*)d_in[5 * d + 4];
            const f16* xhd = xh + (size_t)d * NN * 64;
            edge_cm_kernel<<<dim3(1024, 2), 256, 0, stream>>>(
                xhd, ui, di, ua, da, WtU, WtD, b_up, b_down,
                hcm + (size_t)d * 64 * NPAD);
        }
        node_cm_kernel<<<586, 256, 0, stream>>>(hcm, (float*)d_out, W1, b1, W2, b2);
    } else if (ws_size >= fallback_need) {
        // round-5 proven path
        wtrans_kernel<<<32, 256, 0, stream>>>(W_up, W_down, WtU, WtD);
        init2_kernel<<<9375, 256, 0, stream>>>(x0, x1, x2, agg, xh);
        for (int d = 0; d < 3; ++d) {
            const int*   ui = (const int*)  d_in[5 * d + 1];
            const int*   di = (const int*)  d_in[5 * d + 2];
            const float* ua = (const float*)d_in[5 * d + 3];
            const float* da = (const float*)d_in[5 * d + 4];
            const f16* xhd = xh + (size_t)d * NN * 64;
            __half* h = (__half*)(agg + (size_t)d * NN * 64);
            edge4_kernel<<<dim3(1024, 2), 256, 0, stream>>>(
                xhd, ui, di, ua, da, WtU, WtD, b_up, b_down, h);
        }
        node_kernel<<<586, 256, 0, stream>>>(agg, (float*)d_out, W1, b1, W2, b2);
    }
}

// Round 11
// 435.448 us; speedup vs baseline: 12.7474x; 12.7474x over previous
//
#include <hip/hip_runtime.h>
#include <hip/hip_fp16.h>

#define NN 50000
#define NE 300000
#define ETILES (NE / 16)        // 18750
#define NTILES (NN / 16)        // 3125
#define WLDS_STRIDE 136         // 128 + 8 f16 pad

typedef _Float16 f16;
typedef _Float16 f16x4 __attribute__((ext_vector_type(4)));
typedef _Float16 f16x8 __attribute__((ext_vector_type(8)));
typedef float f32x4 __attribute__((ext_vector_type(4)));

__device__ __forceinline__ f16x4 cvt4(float4 v) {
    f16x4 r; r.x = (f16)v.x; r.y = (f16)v.y; r.z = (f16)v.z; r.w = (f16)v.w;
    return r;
}

// ---------------- init: h = 2*x (f16) AND xh = x (f16), 3 levels ----------------
__global__ void init2_kernel(const float* __restrict__ x0, const float* __restrict__ x1,
                             const float* __restrict__ x2,
                             f16* __restrict__ hbase, f16* __restrict__ xhbase) {
    const size_t i = (size_t)blockIdx.x * 256 + threadIdx.x;   // float4 idx; 9375*256 == 3*NN*16
    const int lvl = (int)(i / (NN * 16));
    const size_t li = i - (size_t)lvl * (NN * 16);
    const float* xs = (lvl == 0) ? x0 : (lvl == 1) ? x1 : x2;
    float4 v = ((const float4*)xs)[li];
    f16x4 xo, ho;
    xo.x = (f16)v.x;        xo.y = (f16)v.y;        xo.z = (f16)v.z;        xo.w = (f16)v.w;
    ho.x = (f16)(2.f*v.x);  ho.y = (f16)(2.f*v.y);  ho.z = (f16)(2.f*v.z);  ho.w = (f16)(2.f*v.w);
    ((f16x4*)(xhbase + (size_t)lvl * NN * 64))[li] = xo;
    ((f16x4*)(hbase  + (size_t)lvl * NN * 64))[li] = ho;
}

// ---------------- W transpose: Wt[c][k] = (f16)W[k][c], W is [128][64] ----------------
__global__ void wtrans_kernel(const float* __restrict__ WU, const float* __restrict__ WD,
                              f16* __restrict__ WtU, f16* __restrict__ WtD) {
    const int i = blockIdx.x * 256 + threadIdx.x;   // 32 blocks * 256 = 8192
    const int k = i >> 6, c = i & 63;
    WtU[c * 128 + k] = (f16)WU[i];
    WtD[c * 128 + k] = (f16)WD[i];
}

// ---------------- edge MLP + f16-pk atomic scatter (R5-proven), 2-deep pipeline ----------------
__device__ __forceinline__ int ld_comb(const int* __restrict__ idx, int tile, int l5) {
    const int e0 = tile << 4;
    return idx[(l5 < 16) ? (NE + e0 + l5) : (e0 + l5 - 16)];
}

__global__ __launch_bounds__(256) void edge4_kernel(
    const f16* __restrict__ xh,
    const int* __restrict__ ui, const int* __restrict__ di,
    const float* __restrict__ ua, const float* __restrict__ da,
    const f16* __restrict__ WtU, const f16* __restrict__ WtD,
    const float* __restrict__ bU, const float* __restrict__ bD,
    __half* __restrict__ h) {

    __shared__ __align__(16) f16 Wlds[64 * WLDS_STRIDE];

    const int dir = blockIdx.y;
    const int* __restrict__ idx    = dir ? di : ui;
    const float* __restrict__ attr = dir ? da : ua;
    const f16* __restrict__ Wt     = dir ? WtD : WtU;
    const float* __restrict__ b    = dir ? bD : bU;

    const int tt   = threadIdx.x;
    const int lane = tt & 63;
    const int wid  = tt >> 6;
    const int lr   = lane & 15;
    const int lg   = (lane >> 4) & 3;
    const int l5   = lane & 31;

    // stage W into LDS (64 rows x 128 f16, padded stride)
    for (int i = tt; i < 1024; i += 256) {
        const int row = i >> 4, seg = i & 15;
        *(f16x8*)&Wlds[row * WLDS_STRIDE + seg * 8] = *(const f16x8*)&Wt[row * 128 + seg * 8];
    }
    float bf[4];
#pragma unroll
    for (int n = 0; n < 4; ++n) bf[n] = b[n * 16 + lr];
    __syncthreads();

    const float4* a4 = (const float4*)attr;

    const int S = gridDim.x * 4;
    int t = blockIdx.x * 4 + wid;
    if (t >= ETILES) return;

    // prologue: comb for tiles t and t+S; gather + attr for tile t
    int cB;
    int srcT, tgT[4];
    f16x4 gx[4];
    float4 pA[4];
    {
        const int cA = ld_comb(idx, t, l5);
        const int tn1 = t + S;
        cB = ld_comb(idx, (tn1 < ETILES) ? tn1 : t, l5);
        srcT = __shfl(cA, lr);
#pragma unroll
        for (int j = 0; j < 4; ++j) tgT[j] = __shfl(cA, 16 + 4 * lg + j);
        const int e0 = t << 4;
#pragma unroll
        for (int k0 = 0; k0 < 4; ++k0)
            gx[k0] = *(const f16x4*)&xh[(size_t)srcT * 64 + k0 * 16 + 4 * lg];
#pragma unroll
        for (int k0 = 0; k0 < 4; ++k0)
            pA[k0] = a4[(size_t)(e0 + lr) * 16 + 4 * k0 + lg];
    }

    for (; t < ETILES; t += S) {
        const int tn  = t + S;
        const int tnn = tn + S;

        // decode next tile's indices (cB arrived ~1 iter ago), issue next-next idx
        const int srcN = __shfl(cB, lr);
        int tgN[4];
#pragma unroll
        for (int j = 0; j < 4; ++j) tgN[j] = __shfl(cB, 16 + 4 * lg + j);
        const int cC = ld_comb(idx, (tnn < ETILES) ? tnn : t, l5);

        // issue next tile's gather + attr (clamped when past end; results unused)
        const int tnc   = (tn < ETILES) ? tn : t;
        const int srcNc = (tn < ETILES) ? srcN : srcT;
        f16x4 gxN[4];
        float4 pAN[4];
        {
            const int e0n = tnc << 4;
#pragma unroll
            for (int k0 = 0; k0 < 4; ++k0)
                gxN[k0] = *(const f16x4*)&xh[(size_t)srcNc * 64 + k0 * 16 + 4 * lg];
#pragma unroll
            for (int k0 = 0; k0 < 4; ++k0)
                pAN[k0] = a4[(size_t)(e0n + lr) * 16 + 4 * k0 + lg];
        }

        // fragments for current tile
        f16x4 afr[8];
#pragma unroll
        for (int k0 = 0; k0 < 4; ++k0) afr[k0] = gx[k0];
#pragma unroll
        for (int k0 = 0; k0 < 4; ++k0) afr[4 + k0] = cvt4(pA[k0]);

        f32x4 acc[4];
#pragma unroll
        for (int n = 0; n < 4; ++n) acc[n] = (f32x4){0.f, 0.f, 0.f, 0.f};
#pragma unroll
        for (int k0 = 0; k0 < 8; ++k0) {
#pragma unroll
            for (int n = 0; n < 4; ++n) {
                const f16x4 wf = *(const f16x4*)&Wlds[(n * 16 + lr) * WLDS_STRIDE + k0 * 16 + 4 * lg];
                acc[n] = __builtin_amdgcn_mfma_f32_16x16x16f16(afr[k0], wf, acc[n], 0, 0, 0);
            }
        }

        // bias + relu + packed f16 atomic scatter. D[row=4*lg+j][col=n*16+lr].
#pragma unroll
        for (int j = 0; j < 4; ++j) {
            float v[4], vn[4];
#pragma unroll
            for (int n = 0; n < 4; ++n) v[n] = fmaxf(acc[n][j] + bf[n], 0.f);
#pragma unroll
            for (int n = 0; n < 4; ++n) vn[n] = __shfl_xor(v[n], 1);
            __half* hp = h + (size_t)tgT[j] * 64;
            if ((lane & 1) == 0) {
                unsafeAtomicAdd((__half2*)(hp + 0 * 16 + lr), __floats2half2_rn(v[0], vn[0]));
                unsafeAtomicAdd((__half2*)(hp + 1 * 16 + lr), __floats2half2_rn(v[1], vn[1]));
            } else {
                unsafeAtomicAdd((__half2*)(hp + 2 * 16 + lr - 1), __floats2half2_rn(vn[2], v[2]));
                unsafeAtomicAdd((__half2*)(hp + 3 * 16 + lr - 1), __floats2half2_rn(vn[3], v[3]));
            }
        }

        // shift pipeline state
        srcT = srcN;
#pragma unroll
        for (int j = 0; j < 4; ++j) tgT[j] = tgN[j];
#pragma unroll
        for (int k0 = 0; k0 < 4; ++k0) { gx[k0] = gxN[k0]; pA[k0] = pAN[k0]; }
        cB = cC;
    }
}

// ---------------- node MLP: one 16-node tile per WAVE, per-wave LDS, no barriers ----------------
__global__ __launch_bounds__(256) void node_kernel(
    const f16* __restrict__ hbase, float* __restrict__ outb,
    const float* __restrict__ W1, const float* __restrict__ b1,
    const float* __restrict__ W2, const float* __restrict__ b2) {

    __shared__ f16 Y[4][16 * 72];

    const int t    = threadIdx.x;
    const int lane = t & 63;
    const int wid  = t >> 6;
    const int lr   = lane & 15;
    const int lg   = (lane >> 4) & 3;

    f16x4 w1f[4][4], w2f[4][4];
#pragma unroll
    for (int k0 = 0; k0 < 4; ++k0) {
        const int kb = k0 * 16 + 4 * lg;
#pragma unroll
        for (int n = 0; n < 4; ++n) {
            const int c = n * 16 + lr;
            f16x4 wv;
            wv.x = (f16)W1[(kb + 0) * 64 + c];
            wv.y = (f16)W1[(kb + 1) * 64 + c];
            wv.z = (f16)W1[(kb + 2) * 64 + c];
            wv.w = (f16)W1[(kb + 3) * 64 + c];
            w1f[k0][n] = wv;
            wv.x = (f16)W2[(kb + 0) * 64 + c];
            wv.y = (f16)W2[(kb + 1) * 64 + c];
            wv.z = (f16)W2[(kb + 2) * 64 + c];
            wv.w = (f16)W2[(kb + 3) * 64 + c];
            w2f[k0][n] = wv;
        }
    }
    float b1f[4], b2f[4];
#pragma unroll
    for (int n = 0; n < 4; ++n) {
        b1f[n] = b1[n * 16 + lr];
        b2f[n] = b2[n * 16 + lr];
    }

    const int gw     = blockIdx.x * 4 + wid;
    const int stride = gridDim.x * 4;
    for (int tile = gw; tile < 3 * NTILES; tile += stride) {
        const int lvl = tile / NTILES;
        const int n0  = (tile - lvl * NTILES) << 4;
        float* out = outb + (size_t)lvl * NN * 64;
        const f16* h16 = hbase + (size_t)lvl * NN * 64;

        f16x4 a[4];
#pragma unroll
        for (int k0 = 0; k0 < 4; ++k0)
            a[k0] = *(const f16x4*)&h16[(size_t)(n0 + lr) * 64 + k0 * 16 + 4 * lg];

        f32x4 acc[4];
#pragma unroll
        for (int n = 0; n < 4; ++n) acc[n] = (f32x4){0.f, 0.f, 0.f, 0.f};
#pragma unroll
        for (int k0 = 0; k0 < 4; ++k0)
#pragma unroll
            for (int n = 0; n < 4; ++n)
                acc[n] = __builtin_amdgcn_mfma_f32_16x16x16f16(a[k0], w1f[k0][n], acc[n], 0, 0, 0);

#pragma unroll
        for (int n = 0; n < 4; ++n)
#pragma unroll
            for (int j = 0; j < 4; ++j) {
                float v = acc[n][j] + b1f[n];
                v = v > 0.f ? v : 0.f;
                Y[wid][(4 * lg + j) * 72 + n * 16 + lr] = (f16)v;
            }

        f16x4 a2[4];
#pragma unroll
        for (int k0 = 0; k0 < 4; ++k0)
            a2[k0] = *(const f16x4*)&Y[wid][lr * 72 + k0 * 16 + 4 * lg];

        f32x4 acc2[4];
#pragma unroll
        for (int n = 0; n < 4; ++n) acc2[n] = (f32x4){0.f, 0.f, 0.f, 0.f};
#pragma unroll
        for (int k0 = 0; k0 < 4; ++k0)
#pragma unroll
            for (int n = 0; n < 4; ++n)
                acc2[n] = __builtin_amdgcn_mfma_f32_16x16x16f16(a2[k0], w2f[k0][n], acc2[n], 0, 0, 0);

#pragma unroll
        for (int n = 0; n < 4; ++n)
#pragma unroll
            for (int j = 0; j < 4; ++j) {
                float v = acc2[n][j] + b2f[n];
                v = v > 0.f ? v : 0.f;
                out[(size_t)(n0 + 4 * lg + j) * 64 + n * 16 + lr] = v;
            }
    }
}

extern "C" void kernel_launch(void* const* d_in, const int* in_sizes, int n_in,
                              void* d_out, int out_size, void* d_ws, size_t ws_size,
                              hipStream_t stream) {
    (void)in_sizes; (void)n_in; (void)out_size; (void)ws_size;

    const float* W_up   = (const float*)d_in[15];
    const float* b_up   = (const float*)d_in[16];
    const float* W_down = (const float*)d_in[17];
    const float* b_down = (const float*)d_in[18];
    const float* W1     = (const float*)d_in[19];
    const float* b1     = (const float*)d_in[20];
    const float* W2     = (const float*)d_in[21];
    const float* b2     = (const float*)d_in[22];

    const float* x0 = (const float*)d_in[0];
    const float* x1 = (const float*)d_in[5];
    const float* x2 = (const float*)d_in[10];

    // workspace: hbase (19.2 MB) + xh (19.2 MB) + Wt (32 KB)
    const size_t hbytes = (size_t)3 * NN * 64 * sizeof(f16);
    f16* hbase  = (f16*)d_ws;
    f16* xhbase = hbase + (size_t)3 * NN * 64;
    f16* WtU    = (f16*)((char*)d_ws + 2 * hbytes);
    f16* WtD    = WtU + 128 * 64;

    wtrans_kernel<<<32, 256, 0, stream>>>(W_up, W_down, WtU, WtD);
    init2_kernel<<<9375, 256, 0, stream>>>(x0, x1, x2, hbase, xhbase);

    for (int d = 0; d < 3; ++d) {
        const int*   ui = (const int*)  d_in[5 * d + 1];
        const int*   di = (const int*)  d_in[5 * d + 2];
        const float* ua = (const float*)d_in[5 * d + 3];
        const float* da = (const float*)d_in[5 * d + 4];
        const f16* xhd = xhbase + (size_t)d * NN * 64;
        __half* h = (__half*)(hbase + (size_t)d * NN * 64);
        edge4_kernel<<<dim3(2048, 2), 256, 0, stream>>>(
            xhd, ui, di, ua, da, WtU, WtD, b_up, b_down, h);
    }
    node_kernel<<<586, 256, 0, stream>>>(hbase, (float*)d_out, W1, b1, W2, b2);
}